// Round 9
// baseline (79.856 us; speedup 1.0000x reference)
//
#include <hip/hip_runtime.h>

#define NROWS 4096
#define NCOLS 4096
#define TPB   512   // 2 rows x 256 threads

// Per-row global coeff layout (floats):
// [det0 2048 | det1 1024 | det2 512 | det3 256 | det4 128 | det5 64 | det6 32 | det7 16 | a7 16]
// LDS per row (14.3 KB): P0[2048] ping, P1[1024] pong, Csm[512] (dets3..7 + a7).
// Two rows per block: r = tid>>8 selects row copy, t = tid&255 is within-row tid.

#define LD4(arr, base, vec) { float4 _v = (vec); (arr)[(base)] = _v.x; (arr)[(base)+1] = _v.y; (arr)[(base)+2] = _v.z; (arr)[(base)+3] = _v.w; }
#define LD2(arr, base, vec) { float2 _v = (vec); (arr)[(base)] = _v.x; (arr)[(base)+1] = _v.y; }

// stride-1 taps: E/O are separate (deinterleaved) arrays
__device__ __forceinline__ void fwd_pt(const float* e8, const float* o8,
                                       const float* wl, float& dd, float& aa)
{
    float d = 0.f, a = 0.f;
    #pragma unroll
    for (int t = 0; t < 8; ++t) {
        float e = e8[-t], o = o8[-t];
        d = fmaf(wl[2*t],     e, d);
        d = fmaf(wl[2*t+1],   o, d);
        a = fmaf(wl[15-2*t],  e, a);
        a = fmaf(-wl[14-2*t], o, a);
    }
    dd = d; aa = a;
}

// stride-2 taps: window is the RAW interleaved x row (E[k-t]=x[2(k-t)])
__device__ __forceinline__ void fwd_pt2(const float* e8, const float* o8,
                                        const float* wl, float& dd, float& aa)
{
    float d = 0.f, a = 0.f;
    #pragma unroll
    for (int t = 0; t < 8; ++t) {
        float e = e8[-2*t], o = o8[-2*t];
        d = fmaf(wl[2*t],     e, d);
        d = fmaf(wl[2*t+1],   o, d);
        a = fmaf(wl[15-2*t],  e, a);
        a = fmaf(-wl[14-2*t], o, a);
    }
    dd = d; aa = a;
}

__device__ __forceinline__ void bwd_pt(const float* d8, const float* a8,
                                       const float* wl, float& rr0, float& rr1)
{
    float x = 0.f, y = 0.f;
    #pragma unroll
    for (int t = 0; t < 8; ++t) {
        float dv = d8[-t], av = a8[-t];
        x = fmaf(wl[15-2*t], dv, x);
        x = fmaf(wl[2*t],    av, x);
        y = fmaf(wl[14-2*t], dv, y);
        y = fmaf(-wl[2*t+1], av, y);
    }
    rr0 = x; rr1 = y;
}

__global__ __launch_bounds__(TPB, 8) void despawn_kernel(
    const float* __restrict__ in, const float* __restrict__ wv,
    float* __restrict__ out_rec, float* __restrict__ out_coef)
{
    __shared__ float P0s[2][2048];
    __shared__ float P1s[2][1024];
    __shared__ float Csms[2][512];

    const int tid = threadIdx.x;
    const int r   = tid >> 8;        // row within block
    const int t   = tid & 255;       // within-row thread id
    float* P0  = P0s[r];
    float* P1  = P1s[r];
    float* Csm = Csms[r];

    const int row = blockIdx.x * 2 + r;
    const float* rowIn = in + (size_t)row * NCOLS;
    float* crow = out_coef + (size_t)row * NCOLS;
    float* rrow = out_rec  + (size_t)row * NCOLS;

    float wl[16];

    // ===== fwd level 0: global x -> det0(global), E1->P0[0..1023], O1->P0[1024..2047]
    {
        #pragma unroll
        for (int q = 0; q < 16; ++q) wl[q] = wv[q];
        const float4* X4 = (const float4*)rowIn;           // 1024 chunks
        float xw[32];                                      // x[(16t-16+i)&4095]
        #pragma unroll
        for (int j = 0; j < 8; ++j) LD4(xw, 4*j, X4[(4*t - 4 + j) & 1023]);
        float d[8], a[8];
        #pragma unroll
        for (int p = 0; p < 8; ++p) fwd_pt2(&xw[16 + 2*p], &xw[17 + 2*p], wl, d[p], a[p]);
        const int k0 = t * 8;
        ((float4*)(crow + k0))[0] = make_float4(d[0], d[1], d[2], d[3]);
        ((float4*)(crow + k0))[1] = make_float4(d[4], d[5], d[6], d[7]);
        *(float4*)(P0 + (k0 >> 1))        = make_float4(a[0], a[2], a[4], a[6]);  // E1
        *(float4*)(P0 + 1024 + (k0 >> 1)) = make_float4(a[1], a[3], a[5], a[7]);  // O1
    }
    __syncthreads();

    // ===== fwd level 1: P0 -> det1(global), E2->P1[0..511], O2->P1[512..1023]
    {
        #pragma unroll
        for (int q = 0; q < 16; ++q) wl[q] = wv[16 + q];
        const float4* E4 = (const float4*)P0;              // 256 chunks
        const float4* O4 = (const float4*)(P0 + 1024);
        float xe[12], xo[12];
        #pragma unroll
        for (int j = 0; j < 3; ++j) {
            int idx = (t - 2 + j) & 255;
            LD4(xe, 4*j, E4[idx]); LD4(xo, 4*j, O4[idx]);
        }
        float d[4], a[4];
        #pragma unroll
        for (int p = 0; p < 4; ++p) fwd_pt(&xe[8 + p], &xo[8 + p], wl, d[p], a[p]);
        const int k0 = t * 4;
        *(float4*)(crow + 2048 + k0) = make_float4(d[0], d[1], d[2], d[3]);
        *(float2*)(P1 + (k0 >> 1))       = make_float2(a[0], a[2]);
        *(float2*)(P1 + 512 + (k0 >> 1)) = make_float2(a[1], a[3]);
    }
    __syncthreads();

    // ===== fwd level 2: P1 -> det2(global), E3->P0[0..255], O3->P0[256..511]
    {
        #pragma unroll
        for (int q = 0; q < 16; ++q) wl[q] = wv[32 + q];
        const float2* Ev = (const float2*)P1;              // 256 chunks
        const float2* Ov = (const float2*)(P1 + 512);
        float xe[10], xo[10];
        #pragma unroll
        for (int j = 0; j < 5; ++j) {
            int idx = (t - 4 + j) & 255;
            LD2(xe, 2*j, Ev[idx]); LD2(xo, 2*j, Ov[idx]);
        }
        float d[2], a[2];
        #pragma unroll
        for (int p = 0; p < 2; ++p) fwd_pt(&xe[8 + p], &xo[8 + p], wl, d[p], a[p]);
        const int k0 = t * 2;
        *(float2*)(crow + 3072 + k0) = make_float2(d[0], d[1]);
        P0[t]       = a[0];
        P0[256 + t] = a[1];
    }
    __syncthreads();

    // ===== fwd levels 3..7: bump in P0[512..1023], dets -> Csm + global
    {
        const float* Ein = P0;         // E@Ein[0..part-1], O@Ein[part..2*part-1]
        float* aout = P0 + 512;
        int part = 256, cs = 0, cg = 3584;
        for (int lvl = 3; lvl < 8; ++lvl) {
            #pragma unroll
            for (int q = 0; q < 16; ++q) wl[q] = wv[16*lvl + q];
            const int nth = part >> 2;
            if (t < nth) {
                const int pm = nth - 1;
                const float4* E4 = (const float4*)Ein;
                const float4* O4 = (const float4*)(Ein + part);
                float xe[12], xo[12];
                #pragma unroll
                for (int j = 0; j < 3; ++j) {
                    int idx = (t - 2 + j) & pm;
                    LD4(xe, 4*j, E4[idx]); LD4(xo, 4*j, O4[idx]);
                }
                float d[4], a[4];
                #pragma unroll
                for (int p = 0; p < 4; ++p) fwd_pt(&xe[8 + p], &xo[8 + p], wl, d[p], a[p]);
                const int k0 = t * 4;
                float4 dv = make_float4(d[0], d[1], d[2], d[3]);
                *(float4*)(Csm + cs + k0)  = dv;
                *(float4*)(crow + cg + k0) = dv;
                if (lvl == 7) {
                    float4 av = make_float4(a[0], a[1], a[2], a[3]);
                    *(float4*)(Csm + 496 + k0)   = av;
                    *(float4*)(crow + 4080 + k0) = av;
                } else {
                    *(float2*)(aout + (k0 >> 1))               = make_float2(a[0], a[2]);
                    *(float2*)(aout + (part >> 1) + (k0 >> 1)) = make_float2(a[1], a[3]);
                }
            }
            __syncthreads();
            Ein = aout; aout += part; cs += part; cg += part; part >>= 1;
        }
    }

    // ===== bwd levels 7..3: D from Csm, out -> bump P0[1024..2015]; A3 = P0[1504..2015]
    const float* A = Csm + 496;   // a7
    {
        float* outp = P0 + 1024;
        int md = 16, dOff = 480;
        for (int lvl = 7; lvl >= 3; --lvl) {
            #pragma unroll
            for (int q = 0; q < 16; ++q) wl[q] = wv[16*lvl + q];
            const int nth = md >> 2;
            if (t < nth) {
                const int pm = nth - 1;
                const float4* D4 = (const float4*)(Csm + dOff);
                const float4* A4 = (const float4*)A;
                float xd[12], xa[12];
                #pragma unroll
                for (int j = 0; j < 3; ++j) {
                    int idx = (t - 2 + j) & pm;
                    LD4(xd, 4*j, D4[idx]); LD4(xa, 4*j, A4[idx]);
                }
                float r0[4], r1[4];
                #pragma unroll
                for (int p = 0; p < 4; ++p) bwd_pt(&xd[8 + p], &xa[8 + p], wl, r0[p], r1[p]);
                const int j0 = t * 4;
                ((float4*)(outp + 2*j0))[0] = make_float4(r0[0], r1[0], r0[1], r1[1]);
                ((float4*)(outp + 2*j0))[1] = make_float4(r0[2], r1[2], r0[3], r1[3]);
            }
            __syncthreads();
            A = outp; outp += 2*md; md <<= 1; dOff -= md;
        }
    }

    // ===== bwd level 2: D=det2(global), A=P0[1504..2015] -> P1[0..1023]
    {
        #pragma unroll
        for (int q = 0; q < 16; ++q) wl[q] = wv[32 + q];
        const float2* Dg = (const float2*)(crow + 3072);   // 256 chunks
        const float2* Av = (const float2*)(P0 + 1504);
        float xd[10], xa[10];
        #pragma unroll
        for (int j = 0; j < 5; ++j) {
            int idx = (t - 4 + j) & 255;
            LD2(xd, 2*j, Dg[idx]); LD2(xa, 2*j, Av[idx]);
        }
        float r0[2], r1[2];
        #pragma unroll
        for (int p = 0; p < 2; ++p) bwd_pt(&xd[8 + p], &xa[8 + p], wl, r0[p], r1[p]);
        const int j0 = t * 2;
        *(float4*)(P1 + 2*j0) = make_float4(r0[0], r1[0], r0[1], r1[1]);
    }
    __syncthreads();

    // ===== bwd level 1: D=det1(global), A=P1[0..1023] -> P0[0..2047]
    {
        #pragma unroll
        for (int q = 0; q < 16; ++q) wl[q] = wv[16 + q];
        const float4* Dg = (const float4*)(crow + 2048);   // 256 chunks
        const float4* Av = (const float4*)P1;
        float xd[12], xa[12];
        #pragma unroll
        for (int j = 0; j < 3; ++j) {
            int idx = (t - 2 + j) & 255;
            LD4(xd, 4*j, Dg[idx]); LD4(xa, 4*j, Av[idx]);
        }
        float r0[4], r1[4];
        #pragma unroll
        for (int p = 0; p < 4; ++p) bwd_pt(&xd[8 + p], &xa[8 + p], wl, r0[p], r1[p]);
        const int j0 = t * 4;
        ((float4*)(P0 + 2*j0))[0] = make_float4(r0[0], r1[0], r0[1], r1[1]);
        ((float4*)(P0 + 2*j0))[1] = make_float4(r0[2], r1[2], r0[3], r1[3]);
    }
    __syncthreads();

    // ===== bwd level 0: D=det0(global), A=P0 -> rec(global), two halves
    {
        #pragma unroll
        for (int q = 0; q < 16; ++q) wl[q] = wv[q];
        const float4* Dg = (const float4*)crow;            // 512 chunks
        const float4* Av = (const float4*)P0;
        const int j0 = t * 8;
        {   // half A: j = j0..j0+3
            float xd[12], xa[12];
            #pragma unroll
            for (int c = 0; c < 3; ++c) {
                int idx = (2*t - 2 + c) & 511;
                LD4(xd, 4*c, Dg[idx]); LD4(xa, 4*c, Av[idx]);
            }
            float r0[4], r1[4];
            #pragma unroll
            for (int p = 0; p < 4; ++p) bwd_pt(&xd[8 + p], &xa[8 + p], wl, r0[p], r1[p]);
            ((float4*)(rrow + 2*j0))[0] = make_float4(r0[0], r1[0], r0[1], r1[1]);
            ((float4*)(rrow + 2*j0))[1] = make_float4(r0[2], r1[2], r0[3], r1[3]);
        }
        {   // half B: j = j0+4..j0+7
            float xd[12], xa[12];
            #pragma unroll
            for (int c = 0; c < 3; ++c) {
                int idx = (2*t - 1 + c) & 511;
                LD4(xd, 4*c, Dg[idx]); LD4(xa, 4*c, Av[idx]);
            }
            float r0[4], r1[4];
            #pragma unroll
            for (int p = 0; p < 4; ++p) bwd_pt(&xd[8 + p], &xa[8 + p], wl, r0[p], r1[p]);
            ((float4*)(rrow + 2*j0))[2] = make_float4(r0[0], r1[0], r0[1], r1[1]);
            ((float4*)(rrow + 2*j0))[3] = make_float4(r0[2], r1[2], r0[3], r1[3]);
        }
    }
}

extern "C" void kernel_launch(void* const* d_in, const int* in_sizes, int n_in,
                              void* d_out, int out_size, void* d_ws, size_t ws_size,
                              hipStream_t stream) {
    (void)in_sizes; (void)n_in; (void)d_ws; (void)ws_size; (void)out_size;
    const float* in = (const float*)d_in[0];
    const float* wv = (const float*)d_in[1];
    float* out_rec  = (float*)d_out;
    float* out_coef = (float*)d_out + (size_t)NROWS * NCOLS;
    despawn_kernel<<<NROWS / 2, TPB, 0, stream>>>(in, wv, out_rec, out_coef);
}

// Round 10
// 56.244 us; speedup vs baseline: 1.4198x; 1.4198x over previous
//
#include <hip/hip_runtime.h>

#define NROWS 4096
#define NCOLS 4096
#define TPB   256

// Global coeff row layout (floats):
// [det0 2048 | det1 1024 | det2 512 | det3 256 | det4 128 | det5 64 | det6 32 | det7 16 | a7 16]
// LDS: P0[2048] ping, P1[1024] pong, Csm[512] = mirror of global offsets 3584..4095.

__global__ __launch_bounds__(TPB, 8) void despawn_kernel(
    const float* __restrict__ in, const float* __restrict__ wv,
    float* __restrict__ out_rec, float* __restrict__ out_coef)
{
    __shared__ float P0[2048];
    __shared__ float P1[1024];
    __shared__ float Csm[512];

    const int tid = threadIdx.x;
    const int row = blockIdx.x;
    const float* rowIn = in + (size_t)row * NCOLS;
    float* crow = out_coef + (size_t)row * NCOLS;
    float* rrow = out_rec  + (size_t)row * NCOLS;

    float wl[16];

    // ================= forward level 0: global x -> det0(global), E1|O1 -> P0 =================
    {
        #pragma unroll
        for (int q = 0; q < 16; ++q) wl[q] = wv[q];
        float xw[32];
        const float4* X4 = (const float4*)rowIn;           // 1024 blocks
        #pragma unroll
        for (int j = 0; j < 8; ++j) {
            int q = (4 * tid - 4 + j) & 1023;
            float4 v = X4[q];
            xw[4*j+0]=v.x; xw[4*j+1]=v.y; xw[4*j+2]=v.z; xw[4*j+3]=v.w;
        }
        // xw[i] = x[(16tid-16+i) mod 4096]; E[k-s]=xw[16+2p-2s], O[k-s]=xw[17+2p-2s]
        float d[8], a[8];
        #pragma unroll
        for (int p = 0; p < 8; ++p) {
            float dd = 0.f, aa = 0.f;
            #pragma unroll
            for (int t = 0; t < 8; ++t) {
                float e = xw[16 + 2*p - 2*t];
                float o = xw[17 + 2*p - 2*t];
                dd = fmaf(wl[2*t],     e, dd);
                dd = fmaf(wl[2*t+1],   o, dd);
                aa = fmaf(wl[15-2*t],  e, aa);
                aa = fmaf(-wl[14-2*t], o, aa);
            }
            d[p] = dd; a[p] = aa;
        }
        const int k0 = tid * 8;
        ((float4*)(crow + k0))[0] = make_float4(d[0],d[1],d[2],d[3]);
        ((float4*)(crow + k0))[1] = make_float4(d[4],d[5],d[6],d[7]);
        *(float4*)(P0 + (k0>>1))        = make_float4(a[0],a[2],a[4],a[6]);  // E1
        *(float4*)(P0 + 1024 + (k0>>1)) = make_float4(a[1],a[3],a[5],a[7]);  // O1
    }
    __syncthreads();

    // ================= forward level 1: P0 -> det1(global), E2|O2 -> P1 =================
    {
        #pragma unroll
        for (int q = 0; q < 16; ++q) wl[q] = wv[16 + q];
        const float4* E4 = (const float4*)P0;              // 256 blocks
        const float4* O4 = (const float4*)(P0 + 1024);
        float xe[12], xo[12];
        #pragma unroll
        for (int j = 0; j < 3; ++j) {
            int idx = (tid - 2 + j) & 255;
            float4 v = E4[idx], u = O4[idx];
            xe[4*j]=v.x; xe[4*j+1]=v.y; xe[4*j+2]=v.z; xe[4*j+3]=v.w;
            xo[4*j]=u.x; xo[4*j+1]=u.y; xo[4*j+2]=u.z; xo[4*j+3]=u.w;
        }
        float d[4], a[4];
        #pragma unroll
        for (int p = 0; p < 4; ++p) {
            float dd = 0.f, aa = 0.f;
            #pragma unroll
            for (int t = 0; t < 8; ++t) {
                float e = xe[8+p-t], o = xo[8+p-t];
                dd = fmaf(wl[2*t],     e, dd);
                dd = fmaf(wl[2*t+1],   o, dd);
                aa = fmaf(wl[15-2*t],  e, aa);
                aa = fmaf(-wl[14-2*t], o, aa);
            }
            d[p] = dd; a[p] = aa;
        }
        const int k0 = tid * 4;
        *(float4*)(crow + 2048 + k0) = make_float4(d[0],d[1],d[2],d[3]);
        *(float2*)(P1 + (k0>>1))       = make_float2(a[0], a[2]);  // E2
        *(float2*)(P1 + 512 + (k0>>1)) = make_float2(a[1], a[3]);  // O2
    }
    __syncthreads();

    // ================= forward level 2: P1 -> det2(global), E3|O3 -> P0 =================
    {
        #pragma unroll
        for (int q = 0; q < 16; ++q) wl[q] = wv[32 + q];
        const float2* Ev = (const float2*)P1;              // 256 blocks
        const float2* Ov = (const float2*)(P1 + 512);
        float xe[10], xo[10];
        #pragma unroll
        for (int j = 0; j < 5; ++j) {
            int idx = (tid - 4 + j) & 255;
            float2 v = Ev[idx], u = Ov[idx];
            xe[2*j]=v.x; xe[2*j+1]=v.y;
            xo[2*j]=u.x; xo[2*j+1]=u.y;
        }
        float d[2], a[2];
        #pragma unroll
        for (int p = 0; p < 2; ++p) {
            float dd = 0.f, aa = 0.f;
            #pragma unroll
            for (int t = 0; t < 8; ++t) {
                float e = xe[8+p-t], o = xo[8+p-t];
                dd = fmaf(wl[2*t],     e, dd);
                dd = fmaf(wl[2*t+1],   o, dd);
                aa = fmaf(wl[15-2*t],  e, aa);
                aa = fmaf(-wl[14-2*t], o, aa);
            }
            d[p] = dd; a[p] = aa;
        }
        const int k0 = tid * 2;
        *(float2*)(crow + 3072 + k0) = make_float2(d[0], d[1]);
        P0[tid]       = a[0];   // E3 (256)
        P0[256 + tid] = a[1];   // O3
    }
    __syncthreads();

    // ================= forward levels 3..7: LDS ping-pong, det -> Csm + global =================
    {
        float* bin  = P0;
        float* bout = P1;
        int part = 256;      // outputs at this level (= E/O array length)
        int coff = 3584;     // det offset in crow
        for (int lvl = 3; lvl < 8; ++lvl) {
            #pragma unroll
            for (int q = 0; q < 16; ++q) wl[q] = wv[16*lvl + q];
            const int nth = part >> 2;
            if (tid < nth) {
                const int pm = nth - 1;
                const float4* E4 = (const float4*)bin;
                const float4* O4 = (const float4*)(bin + part);
                float xe[12], xo[12];
                #pragma unroll
                for (int j = 0; j < 3; ++j) {
                    int idx = (tid - 2 + j) & pm;
                    float4 v = E4[idx], u = O4[idx];
                    xe[4*j]=v.x; xe[4*j+1]=v.y; xe[4*j+2]=v.z; xe[4*j+3]=v.w;
                    xo[4*j]=u.x; xo[4*j+1]=u.y; xo[4*j+2]=u.z; xo[4*j+3]=u.w;
                }
                float d[4], a[4];
                #pragma unroll
                for (int p = 0; p < 4; ++p) {
                    float dd = 0.f, aa = 0.f;
                    #pragma unroll
                    for (int t = 0; t < 8; ++t) {
                        float e = xe[8+p-t], o = xo[8+p-t];
                        dd = fmaf(wl[2*t],     e, dd);
                        dd = fmaf(wl[2*t+1],   o, dd);
                        aa = fmaf(wl[15-2*t],  e, aa);
                        aa = fmaf(-wl[14-2*t], o, aa);
                    }
                    d[p] = dd; a[p] = aa;
                }
                const int k0 = tid * 4;
                float4 dv = make_float4(d[0],d[1],d[2],d[3]);
                *(float4*)(crow + coff + k0)        = dv;
                *(float4*)(Csm + (coff - 3584) + k0) = dv;
                if (lvl == 7) {
                    float4 av = make_float4(a[0],a[1],a[2],a[3]);
                    *(float4*)(crow + 4080 + k0) = av;
                    *(float4*)(Csm + 496 + k0)   = av;
                } else {
                    *(float2*)(bout + (k0>>1))              = make_float2(a[0], a[2]);
                    *(float2*)(bout + (part>>1) + (k0>>1))  = make_float2(a[1], a[3]);
                }
            }
            __syncthreads();
            float* tmp = bin; bin = bout; bout = tmp;
            coff += part;
            part >>= 1;
        }
    }

    // ================= backward levels 7..3: D,A from LDS, out -> LDS ping-pong =================
    const float* A = Csm + 496;   // a7
    {
        float* bo   = P0;
        float* balt = P1;
        int md = 16;
        int doffL = 480;          // det7 in Csm
        for (int lvl = 7; lvl >= 3; --lvl) {
            #pragma unroll
            for (int q = 0; q < 16; ++q) wl[q] = wv[16*lvl + q];
            const int nth = md >> 2;
            if (tid < nth) {
                const int pm = nth - 1;
                const float4* D4 = (const float4*)(Csm + doffL);
                const float4* A4 = (const float4*)A;
                float xd[12], xa[12];
                #pragma unroll
                for (int j = 0; j < 3; ++j) {
                    int idx = (tid - 2 + j) & pm;
                    float4 v = D4[idx], u = A4[idx];
                    xd[4*j]=v.x; xd[4*j+1]=v.y; xd[4*j+2]=v.z; xd[4*j+3]=v.w;
                    xa[4*j]=u.x; xa[4*j+1]=u.y; xa[4*j+2]=u.z; xa[4*j+3]=u.w;
                }
                float r0[4], r1[4];
                #pragma unroll
                for (int p = 0; p < 4; ++p) {
                    float a0 = 0.f, a1 = 0.f;
                    #pragma unroll
                    for (int t = 0; t < 8; ++t) {
                        float dv = xd[8+p-t], av = xa[8+p-t];
                        a0 = fmaf(wl[15-2*t], dv, a0);
                        a0 = fmaf(wl[2*t],    av, a0);
                        a1 = fmaf(wl[14-2*t], dv, a1);
                        a1 = fmaf(-wl[2*t+1], av, a1);
                    }
                    r0[p] = a0; r1[p] = a1;
                }
                const int j0 = tid * 4;
                ((float4*)(bo + 2*j0))[0] = make_float4(r0[0],r1[0],r0[1],r1[1]);
                ((float4*)(bo + 2*j0))[1] = make_float4(r0[2],r1[2],r0[3],r1[3]);
            }
            __syncthreads();
            A = bo;
            float* tmp = bo; bo = balt; balt = tmp;
            md <<= 1;
            doffL -= md;
        }
    }
    // now A = P0 (512 floats), md = 512

    // ================= backward level 2: D=global det2, A=P0 -> P1 (1024) =================
    {
        #pragma unroll
        for (int q = 0; q < 16; ++q) wl[q] = wv[32 + q];
        const float2* Dg = (const float2*)(crow + 3072);   // 256 blocks
        const float2* A2 = (const float2*)A;               // 256 blocks
        float xd[10], xa[10];
        #pragma unroll
        for (int j = 0; j < 5; ++j) {
            int idx = (tid - 4 + j) & 255;
            float2 v = Dg[idx], u = A2[idx];
            xd[2*j]=v.x; xd[2*j+1]=v.y;
            xa[2*j]=u.x; xa[2*j+1]=u.y;
        }
        float r0[2], r1[2];
        #pragma unroll
        for (int p = 0; p < 2; ++p) {
            float a0 = 0.f, a1 = 0.f;
            #pragma unroll
            for (int t = 0; t < 8; ++t) {
                float dv = xd[8+p-t], av = xa[8+p-t];
                a0 = fmaf(wl[15-2*t], dv, a0);
                a0 = fmaf(wl[2*t],    av, a0);
                a1 = fmaf(wl[14-2*t], dv, a1);
                a1 = fmaf(-wl[2*t+1], av, a1);
            }
            r0[p] = a0; r1[p] = a1;
        }
        const int j0 = tid * 2;
        *(float4*)(P1 + 2*j0) = make_float4(r0[0],r1[0],r0[1],r1[1]);
    }
    __syncthreads();

    // ================= backward level 1: D=global det1, A=P1 -> P0 (2048) =================
    {
        #pragma unroll
        for (int q = 0; q < 16; ++q) wl[q] = wv[16 + q];
        const float4* Dg = (const float4*)(crow + 2048);   // 256 blocks
        const float4* A4 = (const float4*)P1;              // 256 blocks
        float xd[12], xa[12];
        #pragma unroll
        for (int j = 0; j < 3; ++j) {
            int idx = (tid - 2 + j) & 255;
            float4 v = Dg[idx], u = A4[idx];
            xd[4*j]=v.x; xd[4*j+1]=v.y; xd[4*j+2]=v.z; xd[4*j+3]=v.w;
            xa[4*j]=u.x; xa[4*j+1]=u.y; xa[4*j+2]=u.z; xa[4*j+3]=u.w;
        }
        float r0[4], r1[4];
        #pragma unroll
        for (int p = 0; p < 4; ++p) {
            float a0 = 0.f, a1 = 0.f;
            #pragma unroll
            for (int t = 0; t < 8; ++t) {
                float dv = xd[8+p-t], av = xa[8+p-t];
                a0 = fmaf(wl[15-2*t], dv, a0);
                a0 = fmaf(wl[2*t],    av, a0);
                a1 = fmaf(wl[14-2*t], dv, a1);
                a1 = fmaf(-wl[2*t+1], av, a1);
            }
            r0[p] = a0; r1[p] = a1;
        }
        const int j0 = tid * 4;
        ((float4*)(P0 + 2*j0))[0] = make_float4(r0[0],r1[0],r0[1],r1[1]);
        ((float4*)(P0 + 2*j0))[1] = make_float4(r0[2],r1[2],r0[3],r1[3]);
    }
    __syncthreads();

    // ================= backward level 0: D=global det0, A=P0 -> rec (global) =================
    {
        #pragma unroll
        for (int q = 0; q < 16; ++q) wl[q] = wv[q];
        const float4* Dg = (const float4*)crow;            // 512 blocks
        const float4* A4 = (const float4*)P0;              // 512 blocks
        float xd[16], xa[16];
        #pragma unroll
        for (int j = 0; j < 4; ++j) {
            int idx = (2*tid - 2 + j) & 511;
            float4 v = Dg[idx], u = A4[idx];
            xd[4*j]=v.x; xd[4*j+1]=v.y; xd[4*j+2]=v.z; xd[4*j+3]=v.w;
            xa[4*j]=u.x; xa[4*j+1]=u.y; xa[4*j+2]=u.z; xa[4*j+3]=u.w;
        }
        float r0[8], r1[8];
        #pragma unroll
        for (int p = 0; p < 8; ++p) {
            float a0 = 0.f, a1 = 0.f;
            #pragma unroll
            for (int t = 0; t < 8; ++t) {
                float dv = xd[8+p-t], av = xa[8+p-t];
                a0 = fmaf(wl[15-2*t], dv, a0);
                a0 = fmaf(wl[2*t],    av, a0);
                a1 = fmaf(wl[14-2*t], dv, a1);
                a1 = fmaf(-wl[2*t+1], av, a1);
            }
            r0[p] = a0; r1[p] = a1;
        }
        const int j0 = tid * 8;
        float4* R = (float4*)(rrow + 2*j0);
        R[0] = make_float4(r0[0],r1[0],r0[1],r1[1]);
        R[1] = make_float4(r0[2],r1[2],r0[3],r1[3]);
        R[2] = make_float4(r0[4],r1[4],r0[5],r1[5]);
        R[3] = make_float4(r0[6],r1[6],r0[7],r1[7]);
    }
}

extern "C" void kernel_launch(void* const* d_in, const int* in_sizes, int n_in,
                              void* d_out, int out_size, void* d_ws, size_t ws_size,
                              hipStream_t stream) {
    (void)in_sizes; (void)n_in; (void)d_ws; (void)ws_size; (void)out_size;
    const float* in = (const float*)d_in[0];
    const float* wv = (const float*)d_in[1];
    float* out_rec  = (float*)d_out;
    float* out_coef = (float*)d_out + (size_t)NROWS * NCOLS;
    despawn_kernel<<<NROWS, TPB, 0, stream>>>(in, wv, out_rec, out_coef);
}

// Round 11
// 54.618 us; speedup vs baseline: 1.4621x; 1.0298x over previous
//
#include <hip/hip_runtime.h>

#define NROWS 4096
#define NCOLS 4096
#define TPB   256

// Coeff layout (both LDS C[] and global crow, floats):
// [det0 2048 | det1 1024 | det2 512 | det3 256 | det4 128 | det5 64 | det6 32 | det7 16 | a7 16]
// LDS (28 KB): C[4096] full coeff mirror; P0[2048] ping; P1[1024] pong.
// NO global stores until the tail: hipcc emits s_waitcnt vmcnt(0) before every
// s_barrier, so inline stores serialize an HBM drain into each of the 18 stages.
// All global writes (rec + coeff copy-out) happen after the last barrier.

__global__ __launch_bounds__(TPB, 5) void despawn_kernel(
    const float* __restrict__ in, const float* __restrict__ wv,
    float* __restrict__ out_rec, float* __restrict__ out_coef)
{
    __shared__ float C[4096];
    __shared__ float P0[2048];
    __shared__ float P1[1024];

    const int tid = threadIdx.x;
    const int row = blockIdx.x;
    const float* rowIn = in + (size_t)row * NCOLS;
    float* crow = out_coef + (size_t)row * NCOLS;
    float* rrow = out_rec  + (size_t)row * NCOLS;

    float wl[16];

    // ================= fwd level 0: global x -> det0(C), E1|O1 -> P0 =================
    {
        #pragma unroll
        for (int q = 0; q < 16; ++q) wl[q] = wv[q];
        float xw[32];
        const float4* X4 = (const float4*)rowIn;           // 1024 chunks
        #pragma unroll
        for (int j = 0; j < 8; ++j) {
            int q = (4 * tid - 4 + j) & 1023;
            float4 v = X4[q];
            xw[4*j+0]=v.x; xw[4*j+1]=v.y; xw[4*j+2]=v.z; xw[4*j+3]=v.w;
        }
        float d[8], a[8];
        #pragma unroll
        for (int p = 0; p < 8; ++p) {
            float dd = 0.f, aa = 0.f;
            #pragma unroll
            for (int t = 0; t < 8; ++t) {
                float e = xw[16 + 2*p - 2*t];
                float o = xw[17 + 2*p - 2*t];
                dd = fmaf(wl[2*t],     e, dd);
                dd = fmaf(wl[2*t+1],   o, dd);
                aa = fmaf(wl[15-2*t],  e, aa);
                aa = fmaf(-wl[14-2*t], o, aa);
            }
            d[p] = dd; a[p] = aa;
        }
        const int k0 = tid * 8;
        ((float4*)(C + k0))[0] = make_float4(d[0],d[1],d[2],d[3]);
        ((float4*)(C + k0))[1] = make_float4(d[4],d[5],d[6],d[7]);
        *(float4*)(P0 + (k0>>1))        = make_float4(a[0],a[2],a[4],a[6]);  // E1
        *(float4*)(P0 + 1024 + (k0>>1)) = make_float4(a[1],a[3],a[5],a[7]);  // O1
    }
    __syncthreads();

    // ================= fwd level 1: P0 -> det1(C), E2|O2 -> P1 =================
    {
        #pragma unroll
        for (int q = 0; q < 16; ++q) wl[q] = wv[16 + q];
        const float4* E4 = (const float4*)P0;              // 256 chunks
        const float4* O4 = (const float4*)(P0 + 1024);
        float xe[12], xo[12];
        #pragma unroll
        for (int j = 0; j < 3; ++j) {
            int idx = (tid - 2 + j) & 255;
            float4 v = E4[idx], u = O4[idx];
            xe[4*j]=v.x; xe[4*j+1]=v.y; xe[4*j+2]=v.z; xe[4*j+3]=v.w;
            xo[4*j]=u.x; xo[4*j+1]=u.y; xo[4*j+2]=u.z; xo[4*j+3]=u.w;
        }
        float d[4], a[4];
        #pragma unroll
        for (int p = 0; p < 4; ++p) {
            float dd = 0.f, aa = 0.f;
            #pragma unroll
            for (int t = 0; t < 8; ++t) {
                float e = xe[8+p-t], o = xo[8+p-t];
                dd = fmaf(wl[2*t],     e, dd);
                dd = fmaf(wl[2*t+1],   o, dd);
                aa = fmaf(wl[15-2*t],  e, aa);
                aa = fmaf(-wl[14-2*t], o, aa);
            }
            d[p] = dd; a[p] = aa;
        }
        const int k0 = tid * 4;
        *(float4*)(C + 2048 + k0) = make_float4(d[0],d[1],d[2],d[3]);
        *(float2*)(P1 + (k0>>1))       = make_float2(a[0], a[2]);  // E2
        *(float2*)(P1 + 512 + (k0>>1)) = make_float2(a[1], a[3]);  // O2
    }
    __syncthreads();

    // ================= fwd level 2: P1 -> det2(C), E3|O3 -> P0 =================
    {
        #pragma unroll
        for (int q = 0; q < 16; ++q) wl[q] = wv[32 + q];
        const float2* Ev = (const float2*)P1;              // 256 chunks
        const float2* Ov = (const float2*)(P1 + 512);
        float xe[10], xo[10];
        #pragma unroll
        for (int j = 0; j < 5; ++j) {
            int idx = (tid - 4 + j) & 255;
            float2 v = Ev[idx], u = Ov[idx];
            xe[2*j]=v.x; xe[2*j+1]=v.y;
            xo[2*j]=u.x; xo[2*j+1]=u.y;
        }
        float d[2], a[2];
        #pragma unroll
        for (int p = 0; p < 2; ++p) {
            float dd = 0.f, aa = 0.f;
            #pragma unroll
            for (int t = 0; t < 8; ++t) {
                float e = xe[8+p-t], o = xo[8+p-t];
                dd = fmaf(wl[2*t],     e, dd);
                dd = fmaf(wl[2*t+1],   o, dd);
                aa = fmaf(wl[15-2*t],  e, aa);
                aa = fmaf(-wl[14-2*t], o, aa);
            }
            d[p] = dd; a[p] = aa;
        }
        const int k0 = tid * 2;
        *(float2*)(C + 3072 + k0) = make_float2(d[0], d[1]);
        P0[tid]       = a[0];   // E3 (256)
        P0[256 + tid] = a[1];   // O3
    }
    __syncthreads();

    // ================= fwd levels 3..7: LDS ping-pong, det -> C =================
    {
        float* bin  = P0;
        float* bout = P1;
        int part = 256;      // outputs at this level
        int coff = 3584;     // det offset in C
        for (int lvl = 3; lvl < 8; ++lvl) {
            #pragma unroll
            for (int q = 0; q < 16; ++q) wl[q] = wv[16*lvl + q];
            const int nth = part >> 2;
            if (tid < nth) {
                const int pm = nth - 1;
                const float4* E4 = (const float4*)bin;
                const float4* O4 = (const float4*)(bin + part);
                float xe[12], xo[12];
                #pragma unroll
                for (int j = 0; j < 3; ++j) {
                    int idx = (tid - 2 + j) & pm;
                    float4 v = E4[idx], u = O4[idx];
                    xe[4*j]=v.x; xe[4*j+1]=v.y; xe[4*j+2]=v.z; xe[4*j+3]=v.w;
                    xo[4*j]=u.x; xo[4*j+1]=u.y; xo[4*j+2]=u.z; xo[4*j+3]=u.w;
                }
                float d[4], a[4];
                #pragma unroll
                for (int p = 0; p < 4; ++p) {
                    float dd = 0.f, aa = 0.f;
                    #pragma unroll
                    for (int t = 0; t < 8; ++t) {
                        float e = xe[8+p-t], o = xo[8+p-t];
                        dd = fmaf(wl[2*t],     e, dd);
                        dd = fmaf(wl[2*t+1],   o, dd);
                        aa = fmaf(wl[15-2*t],  e, aa);
                        aa = fmaf(-wl[14-2*t], o, aa);
                    }
                    d[p] = dd; a[p] = aa;
                }
                const int k0 = tid * 4;
                *(float4*)(C + coff + k0) = make_float4(d[0],d[1],d[2],d[3]);
                if (lvl == 7) {
                    *(float4*)(C + 4080 + k0) = make_float4(a[0],a[1],a[2],a[3]);
                } else {
                    *(float2*)(bout + (k0>>1))              = make_float2(a[0], a[2]);
                    *(float2*)(bout + (part>>1) + (k0>>1))  = make_float2(a[1], a[3]);
                }
            }
            __syncthreads();
            float* tmp = bin; bin = bout; bout = tmp;
            coff += part;
            part >>= 1;
        }
    }

    // ================= bwd levels 7..3: D,A from C, out -> LDS ping-pong =================
    const float* A = C + 4080;   // a7
    {
        float* bo   = P0;
        float* balt = P1;
        int md = 16;
        int dOff = 4064;          // det7 in C
        for (int lvl = 7; lvl >= 3; --lvl) {
            #pragma unroll
            for (int q = 0; q < 16; ++q) wl[q] = wv[16*lvl + q];
            const int nth = md >> 2;
            if (tid < nth) {
                const int pm = nth - 1;
                const float4* D4 = (const float4*)(C + dOff);
                const float4* A4 = (const float4*)A;
                float xd[12], xa[12];
                #pragma unroll
                for (int j = 0; j < 3; ++j) {
                    int idx = (tid - 2 + j) & pm;
                    float4 v = D4[idx], u = A4[idx];
                    xd[4*j]=v.x; xd[4*j+1]=v.y; xd[4*j+2]=v.z; xd[4*j+3]=v.w;
                    xa[4*j]=u.x; xa[4*j+1]=u.y; xa[4*j+2]=u.z; xa[4*j+3]=u.w;
                }
                float r0[4], r1[4];
                #pragma unroll
                for (int p = 0; p < 4; ++p) {
                    float a0 = 0.f, a1 = 0.f;
                    #pragma unroll
                    for (int t = 0; t < 8; ++t) {
                        float dv = xd[8+p-t], av = xa[8+p-t];
                        a0 = fmaf(wl[15-2*t], dv, a0);
                        a0 = fmaf(wl[2*t],    av, a0);
                        a1 = fmaf(wl[14-2*t], dv, a1);
                        a1 = fmaf(-wl[2*t+1], av, a1);
                    }
                    r0[p] = a0; r1[p] = a1;
                }
                const int j0 = tid * 4;
                ((float4*)(bo + 2*j0))[0] = make_float4(r0[0],r1[0],r0[1],r1[1]);
                ((float4*)(bo + 2*j0))[1] = make_float4(r0[2],r1[2],r0[3],r1[3]);
            }
            __syncthreads();
            A = bo;
            float* tmp = bo; bo = balt; balt = tmp;
            md <<= 1;
            dOff -= md;
        }
    }
    // now A = P0 (512 floats), md = 512

    // ================= bwd level 2: D=det2(C), A=P0 -> P1 (1024) =================
    {
        #pragma unroll
        for (int q = 0; q < 16; ++q) wl[q] = wv[32 + q];
        const float2* Dg = (const float2*)(C + 3072);      // 256 chunks
        const float2* A2 = (const float2*)A;               // 256 chunks
        float xd[10], xa[10];
        #pragma unroll
        for (int j = 0; j < 5; ++j) {
            int idx = (tid - 4 + j) & 255;
            float2 v = Dg[idx], u = A2[idx];
            xd[2*j]=v.x; xd[2*j+1]=v.y;
            xa[2*j]=u.x; xa[2*j+1]=u.y;
        }
        float r0[2], r1[2];
        #pragma unroll
        for (int p = 0; p < 2; ++p) {
            float a0 = 0.f, a1 = 0.f;
            #pragma unroll
            for (int t = 0; t < 8; ++t) {
                float dv = xd[8+p-t], av = xa[8+p-t];
                a0 = fmaf(wl[15-2*t], dv, a0);
                a0 = fmaf(wl[2*t],    av, a0);
                a1 = fmaf(wl[14-2*t], dv, a1);
                a1 = fmaf(-wl[2*t+1], av, a1);
            }
            r0[p] = a0; r1[p] = a1;
        }
        const int j0 = tid * 2;
        *(float4*)(P1 + 2*j0) = make_float4(r0[0],r1[0],r0[1],r1[1]);
    }
    __syncthreads();

    // ================= bwd level 1: D=det1(C), A=P1 -> P0 (2048) =================
    {
        #pragma unroll
        for (int q = 0; q < 16; ++q) wl[q] = wv[16 + q];
        const float4* Dg = (const float4*)(C + 2048);      // 256 chunks
        const float4* A4 = (const float4*)P1;              // 256 chunks
        float xd[12], xa[12];
        #pragma unroll
        for (int j = 0; j < 3; ++j) {
            int idx = (tid - 2 + j) & 255;
            float4 v = Dg[idx], u = A4[idx];
            xd[4*j]=v.x; xd[4*j+1]=v.y; xd[4*j+2]=v.z; xd[4*j+3]=v.w;
            xa[4*j]=u.x; xa[4*j+1]=u.y; xa[4*j+2]=u.z; xa[4*j+3]=u.w;
        }
        float r0[4], r1[4];
        #pragma unroll
        for (int p = 0; p < 4; ++p) {
            float a0 = 0.f, a1 = 0.f;
            #pragma unroll
            for (int t = 0; t < 8; ++t) {
                float dv = xd[8+p-t], av = xa[8+p-t];
                a0 = fmaf(wl[15-2*t], dv, a0);
                a0 = fmaf(wl[2*t],    av, a0);
                a1 = fmaf(wl[14-2*t], dv, a1);
                a1 = fmaf(-wl[2*t+1], av, a1);
            }
            r0[p] = a0; r1[p] = a1;
        }
        const int j0 = tid * 4;
        ((float4*)(P0 + 2*j0))[0] = make_float4(r0[0],r1[0],r0[1],r1[1]);
        ((float4*)(P0 + 2*j0))[1] = make_float4(r0[2],r1[2],r0[3],r1[3]);
    }
    __syncthreads();   // last barrier in the kernel

    // ================= bwd level 0: D=det0(C), A=P0 -> rec (global) =================
    {
        #pragma unroll
        for (int q = 0; q < 16; ++q) wl[q] = wv[q];
        const float4* Dg = (const float4*)C;               // 512 chunks
        const float4* A4 = (const float4*)P0;              // 512 chunks
        float xd[16], xa[16];
        #pragma unroll
        for (int j = 0; j < 4; ++j) {
            int idx = (2*tid - 2 + j) & 511;
            float4 v = Dg[idx], u = A4[idx];
            xd[4*j]=v.x; xd[4*j+1]=v.y; xd[4*j+2]=v.z; xd[4*j+3]=v.w;
            xa[4*j]=u.x; xa[4*j+1]=u.y; xa[4*j+2]=u.z; xa[4*j+3]=u.w;
        }
        float r0[8], r1[8];
        #pragma unroll
        for (int p = 0; p < 8; ++p) {
            float a0 = 0.f, a1 = 0.f;
            #pragma unroll
            for (int t = 0; t < 8; ++t) {
                float dv = xd[8+p-t], av = xa[8+p-t];
                a0 = fmaf(wl[15-2*t], dv, a0);
                a0 = fmaf(wl[2*t],    av, a0);
                a1 = fmaf(wl[14-2*t], dv, a1);
                a1 = fmaf(-wl[2*t+1], av, a1);
            }
            r0[p] = a0; r1[p] = a1;
        }
        const int j0 = tid * 8;
        float4* R = (float4*)(rrow + 2*j0);
        R[0] = make_float4(r0[0],r1[0],r0[1],r1[1]);
        R[1] = make_float4(r0[2],r1[2],r0[3],r1[3]);
        R[2] = make_float4(r0[4],r1[4],r0[5],r1[5]);
        R[3] = make_float4(r0[6],r1[6],r0[7],r1[7]);
    }

    // ================= coeff copy-out: C -> crow, coalesced, no barrier =================
    {
        const float4* C4 = (const float4*)C;               // 1024 chunks
        float4* crow4 = (float4*)crow;
        #pragma unroll
        for (int j = 0; j < 4; ++j)
            crow4[tid + 256 * j] = C4[tid + 256 * j];
    }
}

extern "C" void kernel_launch(void* const* d_in, const int* in_sizes, int n_in,
                              void* d_out, int out_size, void* d_ws, size_t ws_size,
                              hipStream_t stream) {
    (void)in_sizes; (void)n_in; (void)d_ws; (void)ws_size; (void)out_size;
    const float* in = (const float*)d_in[0];
    const float* wv = (const float*)d_in[1];
    float* out_rec  = (float*)d_out;
    float* out_coef = (float*)d_out + (size_t)NROWS * NCOLS;
    despawn_kernel<<<NROWS, TPB, 0, stream>>>(in, wv, out_rec, out_coef);
}